// Round 5
// baseline (810.666 us; speedup 1.0000x reference)
//
#include <hip/hip_runtime.h>

#define NN 100000
#define NE 1600000
#define NBK 196       // ceil(100000/512) dst buckets (512 nodes each)
#define CAP 10240     // per-bucket edge capacity
#define EPB 8192      // edges per block in k_bin
#define LDW 68        // LDS row stride (words): 16B-aligned, 2-way banks

// ---------------- pass 1: bin edges by dst>>9, packed (src<<9)|dst_local ----------------
__global__ __launch_bounds__(256) void k_bin(const int* __restrict__ src,
                                             const int* __restrict__ dst,
                                             int* __restrict__ gcnt,
                                             unsigned int* __restrict__ binned, int E) {
  __shared__ int bcnt[256];
  const int t = threadIdx.x;
  const int e0 = blockIdx.x * EPB;
  bcnt[t] = 0;
  __syncthreads();
  for (int i = 0; i < EPB; i += 256) {
    int e = e0 + i + t;
    if (e < E) atomicAdd(&bcnt[dst[e] >> 9], 1);
  }
  __syncthreads();
  if (t < NBK) {
    int c = bcnt[t];
    bcnt[t] = c ? atomicAdd(&gcnt[t], c) : 0;
  }
  __syncthreads();
  for (int i = 0; i < EPB; i += 256) {
    int e = e0 + i + t;
    if (e < E) {
      int d = dst[e];
      int b = d >> 9;
      int pos = atomicAdd(&bcnt[b], 1);
      if (pos < CAP) binned[(size_t)b * CAP + pos] = ((unsigned int)src[e] << 9) | (d & 511);
    }
  }
}

// ---------------- pass 2: per-bucket local CSR (block-local writes) ----------------
__global__ __launch_bounds__(512) void k_csr(const unsigned int* __restrict__ binned,
                                             const int* __restrict__ gcnt,
                                             int* __restrict__ rowbeg,
                                             int* __restrict__ rowend,
                                             int* __restrict__ eidx, int N) {
  __shared__ int hist[512];
  __shared__ int cur[512];
  const int t = threadIdx.x;
  const int b = blockIdx.x;
  const size_t base = (size_t)b * CAP;
  int cnt = gcnt[b];
  if (cnt > CAP) cnt = CAP;
  hist[t] = 0;
  __syncthreads();
  for (int e = t; e < cnt; e += 512) atomicAdd(&hist[binned[base + e] & 511], 1);
  __syncthreads();
  const int own = hist[t];
  for (int o = 1; o < 512; o <<= 1) {
    int x = (t >= o) ? hist[t - o] : 0;
    __syncthreads();
    hist[t] += x;
    __syncthreads();
  }
  const int incl = hist[t];
  const int excl = incl - own;
  const int node = b * 512 + t;
  if (node < N) {
    rowbeg[node] = (int)base + excl;
    rowend[node] = (int)base + incl;
  }
  cur[t] = excl;
  __syncthreads();
  for (int e = t; e < cnt; e += 512) {
    unsigned int pk = binned[base + e];
    int pos = atomicAdd(&cur[pk & 511], 1);
    eidx[base + pos] = (int)(pk >> 9);
  }
}

// -------- x (row-major) -> blocked [8 planes][N][8]; cg = blockIdx&7 warms its XCD L2 ----
__global__ __launch_bounds__(256) void k_xpose(const float* __restrict__ x,
                                               float* __restrict__ xcb, int N) {
  const int cg = blockIdx.x & 7;
  const int nc = blockIdx.x >> 3;
  const int t = threadIdx.x;
  const int node = nc * 32 + (t >> 3);
  const int lc = t & 7;
  if (node >= N) return;
  xcb[(size_t)cg * (size_t)N * 8 + (size_t)node * 8 + lc] =
      x[(size_t)node * 64 + cg * 8 + lc];
}

// ------- gather-sum on column-blocked layout + fused outer-BN affine ----------
// blockIdx&7 = column group -> pinned (heuristically) to one XCD; per-XCD
// working set = one 3.2MB plane -> L2-resident.
__global__ __launch_bounds__(256) void k_gather(const float* __restrict__ u,
                                                const int* __restrict__ rowbeg,
                                                const int* __restrict__ rowend,
                                                const int* __restrict__ eidx,
                                                const double* __restrict__ st,
                                                const float* __restrict__ g,
                                                const float* __restrict__ bt,
                                                double invN,
                                                float* __restrict__ r, int N) {
  const int cg = blockIdx.x & 7;
  const int nc = blockIdx.x >> 3;
  const int t = threadIdx.x;
  const int node = nc * 32 + (t >> 3);
  const int lc = t & 7;
  if (node >= N) return;
  const size_t N8 = (size_t)N * 8;
  const float* up = u + (size_t)cg * N8;
  const int col = cg * 8 + lc;
  float a = 1.f, d = 0.f;
  if (st) {
    double mu = st[col] * invN;
    double var = st[64 + col] * invN - mu * mu;
    double ai = (double)g[col] / sqrt(var + 1e-5);
    a = (float)ai;
    d = (float)((double)bt[col] - ai * mu);
  }
  int beg = rowbeg[node], end = rowend[node];
  float s = up[(size_t)node * 8 + lc];
  int i = beg;
  for (; i + 4 <= end; i += 4) {
    int s0 = eidx[i], s1 = eidx[i + 1], s2 = eidx[i + 2], s3 = eidx[i + 3];
    float v0 = up[(size_t)s0 * 8 + lc];
    float v1 = up[(size_t)s1 * 8 + lc];
    float v2 = up[(size_t)s2 * 8 + lc];
    float v3 = up[(size_t)s3 * 8 + lc];
    s += v0 + v1 + v2 + v3;
  }
  for (; i < end; ++i) s += up[(size_t)eidx[i] * 8 + lc];
  r[(size_t)cg * N8 + (size_t)node * 8 + lc] = fmaf(a, s, (float)(end - beg + 1) * d);
}

// ================= register-tiled 64x64 GEMMs =================
__device__ __forceinline__ void mm_core(const float* __restrict__ lA,
                                        const float* __restrict__ lW,
                                        int tx, int ty, float4 acc[4]) {
  const int swz = tx & 7;
#pragma unroll
  for (int kk = 0; kk < 16; ++kk) {
    float4 a[4], w[4];
#pragma unroll
    for (int i = 0; i < 4; ++i) a[i] = *(const float4*)(lA + (ty * 4 + i) * LDW + kk * 4);
#pragma unroll
    for (int j = 0; j < 4; ++j)
      w[j] = *(const float4*)(lW + (tx * 4 + j) * LDW + ((kk ^ swz) * 4));
#pragma unroll
    for (int i = 0; i < 4; ++i) {
      float* ai = (float*)&a[i];
      float* ci = (float*)&acc[i];
#pragma unroll
      for (int j = 0; j < 4; ++j) {
        float* wj = (float*)&w[j];
        ci[j] = fmaf(ai[0], wj[0], ci[j]);
        ci[j] = fmaf(ai[1], wj[1], ci[j]);
        ci[j] = fmaf(ai[2], wj[2], ci[j]);
        ci[j] = fmaf(ai[3], wj[3], ci[j]);
      }
    }
  }
}

__device__ __forceinline__ void col_stats(float* red, const float4 acc[4], int nvalid,
                                          int tx, int ty, double* __restrict__ st) {
  float s[4] = {0.f, 0.f, 0.f, 0.f}, q[4] = {0.f, 0.f, 0.f, 0.f};
#pragma unroll
  for (int i = 0; i < 4; ++i) {
    if (i < nvalid) {
      const float* ci = (const float*)&acc[i];
#pragma unroll
      for (int j = 0; j < 4; ++j) {
        s[j] += ci[j];
        q[j] = fmaf(ci[j], ci[j], q[j]);
      }
    }
  }
#pragma unroll
  for (int j = 0; j < 4; ++j) {
    red[(tx * 4 + j) * 16 + ty] = s[j];
    red[1024 + (tx * 4 + j) * 16 + ty] = q[j];
  }
  __syncthreads();
  int t = ty * 16 + tx;
  if (t < 64) {
    double as = 0.0, aq = 0.0;
#pragma unroll
    for (int i = 0; i < 16; ++i) {
      as += red[t * 16 + i];
      aq += red[1024 + t * 16 + i];
    }
    unsafeAtomicAdd(&st[t], as);
    unsafeAtomicAdd(&st[64 + t], aq);
  }
}

// GEMM1: Z = A_blocked @ W + b  (+ column stats of Z); Z row-major
__global__ __launch_bounds__(256) void k_mm1(const float* __restrict__ A,
                                             const float* __restrict__ W,
                                             const float* __restrict__ bias,
                                             float* __restrict__ Z,
                                             double* __restrict__ st, int N) {
  __shared__ float lA[64 * LDW];
  __shared__ float lW[64 * LDW];
  const int t = threadIdx.x;
  const int row0 = blockIdx.x * 64;
  const size_t N8 = (size_t)N * 8;
#pragma unroll
  for (int i = 0; i < 4; ++i) {
    int idx = t + i * 256;
    int r = idx >> 4, c4 = idx & 15;
    float4 v = make_float4(0.f, 0.f, 0.f, 0.f);
    if (row0 + r < N)
      v = *(const float4*)(A + (size_t)(c4 >> 1) * N8 + (size_t)(row0 + r) * 8 + (c4 & 1) * 4);
    *(float4*)(lA + r * LDW + c4 * 4) = v;
  }
#pragma unroll
  for (int i = 0; i < 4; ++i) {
    int idx = t + i * 256;
    int k = idx >> 4, c4 = idx & 15;
    float4 v = *(const float4*)(W + k * 64 + c4 * 4);
    int chs = ((k >> 2) ^ (c4 & 7)) * 4 + (k & 3);
    lW[(4 * c4 + 0) * LDW + chs] = v.x;
    lW[(4 * c4 + 1) * LDW + chs] = v.y;
    lW[(4 * c4 + 2) * LDW + chs] = v.z;
    lW[(4 * c4 + 3) * LDW + chs] = v.w;
  }
  const int tx = t & 15, ty = t >> 4;
  float4 bb = *(const float4*)(bias + tx * 4);
  float4 acc[4] = {bb, bb, bb, bb};
  __syncthreads();
  mm_core(lA, lW, tx, ty, acc);
  int nvalid = N - (row0 + ty * 4);
  nvalid = nvalid < 0 ? 0 : (nvalid > 4 ? 4 : nvalid);
#pragma unroll
  for (int i = 0; i < 4; ++i)
    if (i < nvalid) *(float4*)(Z + (size_t)(row0 + ty * 4 + i) * 64 + tx * 4) = acc[i];
  __syncthreads();
  col_stats(lA, acc, nvalid, tx, ty, st);
}

// GEMM2: OUT = relu_opt( relu(bn(Z)) @ W2 + b2 ); Z row-major; OUT blocked or row-major
template <int OUTC, bool DO_STATS, bool BLOCK_OUT>
__global__ __launch_bounds__(256) void k_mm2(const float* __restrict__ Z,
                                             const double* __restrict__ stz,
                                             const float* __restrict__ g,
                                             const float* __restrict__ bt,
                                             double invN,
                                             const float* __restrict__ W2,
                                             const float* __restrict__ b2,
                                             float* __restrict__ OUT,
                                             double* __restrict__ st, int N) {
  __shared__ float lA[64 * LDW];
  __shared__ float lW[64 * LDW];
  __shared__ float aaf[64], daf[64];
  const int t = threadIdx.x;
  const int row0 = blockIdx.x * 64;
  const size_t N8 = (size_t)N * 8;
  if (t < 64) {
    double mu = stz[t] * invN;
    double var = stz[64 + t] * invN - mu * mu;
    double ai = (double)g[t] / sqrt(var + 1e-5);
    aaf[t] = (float)ai;
    daf[t] = (float)((double)bt[t] - ai * mu);
  }
  __syncthreads();
#pragma unroll
  for (int i = 0; i < 4; ++i) {
    int idx = t + i * 256;
    int r = idx >> 4, c4 = idx & 15;
    float4 v = make_float4(0.f, 0.f, 0.f, 0.f);
    if (row0 + r < N) {
      v = *(const float4*)(Z + (size_t)(row0 + r) * 64 + c4 * 4);
      const float4 av = *(const float4*)(aaf + c4 * 4);
      const float4 dv = *(const float4*)(daf + c4 * 4);
      v.x = fmaxf(fmaf(av.x, v.x, dv.x), 0.f);
      v.y = fmaxf(fmaf(av.y, v.y, dv.y), 0.f);
      v.z = fmaxf(fmaf(av.z, v.z, dv.z), 0.f);
      v.w = fmaxf(fmaf(av.w, v.w, dv.w), 0.f);
    }
    *(float4*)(lA + r * LDW + c4 * 4) = v;
  }
  constexpr int C4 = OUTC / 4;
  for (int idx = t; idx < 16 * OUTC; idx += 256) {
    int k = idx / C4, c4 = idx % C4;
    float4 v = *(const float4*)(W2 + k * OUTC + c4 * 4);
    int chs = ((k >> 2) ^ (c4 & 7)) * 4 + (k & 3);
    lW[(4 * c4 + 0) * LDW + chs] = v.x;
    lW[(4 * c4 + 1) * LDW + chs] = v.y;
    lW[(4 * c4 + 2) * LDW + chs] = v.z;
    lW[(4 * c4 + 3) * LDW + chs] = v.w;
  }
  const int tx = t & 15, ty = t >> 4;
  float4 bb = make_float4(0.f, 0.f, 0.f, 0.f);
  if (tx < C4) bb = *(const float4*)(b2 + tx * 4);
  float4 acc[4] = {bb, bb, bb, bb};
  __syncthreads();
  mm_core(lA, lW, tx, ty, acc);
  int nvalid = N - (row0 + ty * 4);
  nvalid = nvalid < 0 ? 0 : (nvalid > 4 ? 4 : nvalid);
  if (DO_STATS) {
#pragma unroll
    for (int i = 0; i < 4; ++i) {
      float* ci = (float*)&acc[i];
#pragma unroll
      for (int j = 0; j < 4; ++j) ci[j] = fmaxf(ci[j], 0.f);
    }
  }
  if (tx < C4) {
#pragma unroll
    for (int i = 0; i < 4; ++i)
      if (i < nvalid) {
        if (BLOCK_OUT)
          *(float4*)(OUT + (size_t)(tx >> 1) * N8 + (size_t)(row0 + ty * 4 + i) * 8 +
                     (tx & 1) * 4) = acc[i];
        else
          *(float4*)(OUT + (size_t)(row0 + ty * 4 + i) * OUTC + tx * 4) = acc[i];
      }
  }
  if (DO_STATS) {
    __syncthreads();
    col_stats(lA, acc, nvalid, tx, ty, st);
  }
}

// ---------------- log_softmax over 40 cols ----------------
__global__ __launch_bounds__(256) void k_lsm(const float* __restrict__ in,
                                             float* __restrict__ out, int N) {
  __shared__ float lv[256 * 41];
  __shared__ float corr[256];
  const int row0 = blockIdx.x * 256;
  for (int t = threadIdx.x; t < 256 * 40; t += 256) {
    int rr = t / 40, cc = t - rr * 40;
    if (row0 + rr < N) lv[rr * 41 + cc] = in[(size_t)row0 * 40 + t];
  }
  __syncthreads();
  const int r = threadIdx.x;
  if (row0 + r < N) {
    float m = -1e30f;
#pragma unroll
    for (int c = 0; c < 40; ++c) m = fmaxf(m, lv[r * 41 + c]);
    float s = 0.f;
#pragma unroll
    for (int c = 0; c < 40; ++c) s += expf(lv[r * 41 + c] - m);
    corr[r] = m + logf(s);
  }
  __syncthreads();
  for (int t = threadIdx.x; t < 256 * 40; t += 256) {
    int rr = t / 40, cc = t - rr * 40;
    if (row0 + rr < N) out[(size_t)row0 * 40 + t] = lv[rr * 41 + cc] - corr[rr];
  }
}

extern "C" void kernel_launch(void* const* d_in, const int* in_sizes, int n_in,
                              void* d_out, int out_size, void* d_ws, size_t ws_size,
                              hipStream_t stream) {
  const float* x = (const float*)d_in[0];
  const int* src = (const int*)d_in[1];
  const int* dst = (const int*)d_in[2];
  const float *W1[3], *b1[3], *g[3], *bt[3], *W2[3], *b2[3];
  for (int i = 0; i < 3; ++i) {
    W1[i] = (const float*)d_in[3 + i * 6 + 0];
    b1[i] = (const float*)d_in[3 + i * 6 + 1];
    g[i] = (const float*)d_in[3 + i * 6 + 2];
    bt[i] = (const float*)d_in[3 + i * 6 + 3];
    W2[i] = (const float*)d_in[3 + i * 6 + 4];
    b2[i] = (const float*)d_in[3 + i * 6 + 5];
  }
  const float* bng[2] = {(const float*)d_in[21], (const float*)d_in[23]};
  const float* bnb[2] = {(const float*)d_in[22], (const float*)d_in[24]};

  const int N = NN, E = NE;
  const size_t N64 = (size_t)N * 64;

  // workspace layout (~93 MB)
  char* p = (char*)d_ws;
  float* A = (float*)p; p += N64 * 4;            // r buffer (blocked)
  float* B = (float*)p; p += N64 * 4;            // z buffer (row-major)
  float* C = (float*)p; p += N64 * 4;            // h buffer (blocked) / final logits (row-major)
  double* ST = (double*)p; p += 5 * 128 * 8;     // stats
  int* gcnt = (int*)p; p += 256 * 4;
  int* rowbeg = (int*)p; p += (size_t)N * 4;
  int* rowend = (int*)p; p += (size_t)N * 4;
  unsigned int* binned = (unsigned int*)p; p += (size_t)NBK * CAP * 4;
  int* eidx = (int*)p; p += (size_t)NBK * CAP * 4;

  const double invN = 1.0 / (double)N;
  const int ggat = 8 * ((N + 31) / 32);  // 25000
  const int gmm = (N + 63) / 64;         // 1563

  hipMemsetAsync(ST, 0, 5 * 128 * 8 + 256 * 4, stream);

  // ---- CSR build ----
  k_bin<<<(E + EPB - 1) / EPB, 256, 0, stream>>>(src, dst, gcnt, binned, E);
  k_csr<<<NBK, 512, 0, stream>>>(binned, gcnt, rowbeg, rowend, eidx, N);

  // ---- layer 0: x -> blocked in C, then gather C->A ----
  k_xpose<<<ggat, 256, 0, stream>>>(x, C, N);
  k_gather<<<ggat, 256, 0, stream>>>(C, rowbeg, rowend, eidx, (const double*)nullptr,
                                     (const float*)nullptr, (const float*)nullptr, invN, A, N);
  k_mm1<<<gmm, 256, 0, stream>>>(A, W1[0], b1[0], B, ST + 0 * 128, N);
  k_mm2<64, true, true><<<gmm, 256, 0, stream>>>(B, ST + 0 * 128, g[0], bt[0], invN, W2[0],
                                                 b2[0], C, ST + 1 * 128, N);

  // ---- layer 1 ----
  k_gather<<<ggat, 256, 0, stream>>>(C, rowbeg, rowend, eidx, ST + 1 * 128, bng[0], bnb[0], invN,
                                     A, N);
  k_mm1<<<gmm, 256, 0, stream>>>(A, W1[1], b1[1], B, ST + 2 * 128, N);
  k_mm2<64, true, true><<<gmm, 256, 0, stream>>>(B, ST + 2 * 128, g[1], bt[1], invN, W2[1],
                                                 b2[1], C, ST + 3 * 128, N);

  // ---- layer 2 ----
  k_gather<<<ggat, 256, 0, stream>>>(C, rowbeg, rowend, eidx, ST + 3 * 128, bng[1], bnb[1], invN,
                                     A, N);
  k_mm1<<<gmm, 256, 0, stream>>>(A, W1[2], b1[2], B, ST + 4 * 128, N);
  k_mm2<40, false, false><<<gmm, 256, 0, stream>>>(B, ST + 4 * 128, g[2], bt[2], invN, W2[2],
                                                   b2[2], C, (double*)nullptr, N);
  k_lsm<<<(N + 255) / 256, 256, 0, stream>>>(C, (float*)d_out, N);
}